// Round 21
// baseline (45.751 us; speedup 1.0000x reference)
//
#include <hip/hip_runtime.h>

// Policy MLP via split-precision bf16 MFMA (round 21: sched_barrier hoist).
// B=131072, D=32, L=40 hidden + final 32->1.
//
// Round-21 change vs round 20 (single variable): __builtin_amdgcn_sched_barrier(0)
// between the layer-(l+1) prefetch loads and the layer-l compute block.
// Evidence: r13's prefetch was sunk by the scheduler (VGPR stayed 36) and
// r19's bottom-pin only constrained COMPLETION, not ISSUE -- loads still sat
// right before their use. The sched barrier forbids crossing, so the
// ds_reads issue at the top of iteration l and drain under ~500 cyc of
// MFMA+split, making the next iteration's lgkmcnt wait ~free.
// Diagnostic: VGPR_Count must rise to >=64 (two layers of frags live).
//
// Base (r20): 32x32x16 single-acc, 7 MFMAs/wave-layer (1 bias-MFMA via
// ones-trick + 6 product), 4x b128 + 1x b32 LDS per wave-layer, 157KB LDS
// staging (38 layers + packed bias), C=32 cols/wave, 16 waves/CU, full
// unroll, trunc-split via v_perm_b32. pi(kk,h,w,e) permutation on both A
// and B (r3-verified, absmax 0.0).

#define NB 131072
#define DD 32
#define NL 40
#define BIAS_BYTES ((NL + 1) * 32 * 4)       // 5248: packed bf16 hi|lo dwords
#define WTAB_OFF   BIAS_BYTES
#define LDS_LAYERS 38
#define LDS_BYTES  (BIAS_BYTES + LDS_LAYERS * 4096)  // 160896 <= 163840

typedef short bf16x8 __attribute__((ext_vector_type(8)));
typedef float f32x16 __attribute__((ext_vector_type(16)));

union Frag { int4 q; int i[4]; bf16x8 v; };

__device__ inline unsigned f2bf(float f) {  // fp32 -> bf16 bits, RNE
  unsigned u = __float_as_uint(f);
  return (u + 0x7fffu + ((u >> 16) & 1u)) >> 16;
}
__device__ inline float bf2f(unsigned s) { return __int_as_float((int)(s << 16)); }

// ---- table build ----------------------------------------------------------
// d_ws layout: [compact bias 5248 B][wtab 41 layers x 4096 B].
// wtab[l][g][lane]: g=0/1: W hi (kk=0/1); g=2/3: W lo. pi-permuted k order.
// bias[l][m]: bias_hi | bias_lo<<16 (bf16 pair) for output row m.
__global__ __launch_bounds__(64) void build_tables(
    const float* __restrict__ Wh, const float* __restrict__ bh,
    const float* __restrict__ Wout, const float* __restrict__ bout,
    char* __restrict__ ws) {
  const int l = blockIdx.x;      // 0..40 (40 == output layer)
  const int lane = threadIdx.x;  // 0..63
  const int m = lane & 31, h = lane >> 5;
  int4* wtab = (int4*)(ws + WTAB_OFF);
  int* bc = (int*)ws;
  for (int g = 0; g < 4; ++g) {  // {hi,lo} x {kk}
    const int kk = g & 1;
    const bool lopart = (g >= 2);
    int wds[4];
    for (int w = 0; w < 4; ++w) {
      const int k = 16 * kk + 8 * (w >> 1) + 4 * h + 2 * (w & 1);  // pi
      float a, b;
      if (l < NL) {
        a = Wh[(l * 32 + m) * 32 + k];
        b = Wh[(l * 32 + m) * 32 + k + 1];
      } else {  // final layer: row 0 = W_out, rest zero
        a = (m == 0) ? Wout[k] : 0.f;
        b = (m == 0) ? Wout[k + 1] : 0.f;
      }
      unsigned ah = f2bf(a), bhh = f2bf(b);
      unsigned al = f2bf(a - bf2f(ah)), bl = f2bf(b - bf2f(bhh));
      wds[w] = lopart ? (int)(al | (bl << 16)) : (int)(ah | (bhh << 16));
    }
    wtab[(l * 4 + g) * 64 + lane] = make_int4(wds[0], wds[1], wds[2], wds[3]);
  }
  if (lane < 32) {  // compact packed bias (bf16 hi + lo)
    float bv = (l < NL) ? bh[l * 32 + lane] : ((lane == 0) ? bout[0] : 0.f);
    unsigned bhi = f2bf(bv);
    unsigned blo = f2bf(bv - bf2f(bhi));
    bc[l * 32 + lane] = (int)(bhi | (blo << 16));
  }
}

// ---- main kernel ----------------------------------------------------------
// Truncation split: hi = packed high-halves of (a,b) via one v_perm_b32;
// lo = packed high-halves of the exact residuals (x = hi + lo to 2^-16).
__device__ inline void split2(float a, float b, int& hi, int& lo) {
  const unsigned ia = __float_as_uint(a), ib = __float_as_uint(b);
  hi = (int)__builtin_amdgcn_perm(ia, ib, 0x03020706u);
  const float ha = __int_as_float((int)(ia & 0xffff0000u));
  const float hb = __int_as_float((int)(ib & 0xffff0000u));
  const float la = a - ha, lb = b - hb;  // exact
  lo = (int)__builtin_amdgcn_perm(__float_as_uint(la), __float_as_uint(lb),
                                  0x03020706u);
}

#define MFMA32(A, B, C) __builtin_amdgcn_mfma_f32_32x32x16_bf16((A), (B), (C), 0, 0, 0)

__global__ __launch_bounds__(1024, 4) void policy_mfma(
    const float* __restrict__ state, const char* __restrict__ tab,
    float* __restrict__ out) {
  extern __shared__ char smem[];
  const int tid = threadIdx.x;
  const int lane = tid & 63;
  const int n = lane & 31, h = lane >> 5;
  const int wid = blockIdx.x * 16 + (tid >> 6);
  const int bbase = wid * 32;  // 32 batch cols per wave, one 32x32 acc

  // ---- stage compact bias + 38 layers of weights into LDS (one-time) ----
  {
    const int4* src = (const int4*)tab;
    int4* dst = (int4*)smem;
    for (int i = tid; i < LDS_BYTES / 16; i += 1024) dst[i] = src[i];
  }

  // Layer-0 B frags (pi layout, r3-verified):
  // (kk, h, w=0,1) <- x[16kk+4h+0..3]; (w=2,3) <- x[16kk+8+4h+0..3]
  Frag bhi0, bhi1, blo0, blo1;
  {
    const float* xr = state + (size_t)(bbase + n) * DD;
    float4 xa = *(const float4*)(xr + 4 * h);
    float4 xb = *(const float4*)(xr + 8 + 4 * h);
    float4 xc = *(const float4*)(xr + 16 + 4 * h);
    float4 xd = *(const float4*)(xr + 24 + 4 * h);
    split2(xa.x, xa.y, bhi0.i[0], blo0.i[0]);
    split2(xa.z, xa.w, bhi0.i[1], blo0.i[1]);
    split2(xb.x, xb.y, bhi0.i[2], blo0.i[2]);
    split2(xb.z, xb.w, bhi0.i[3], blo0.i[3]);
    split2(xc.x, xc.y, bhi1.i[0], blo1.i[0]);
    split2(xc.z, xc.w, bhi1.i[1], blo1.i[1]);
    split2(xd.x, xd.y, bhi1.i[2], blo1.i[2]);
    split2(xd.z, xd.w, bhi1.i[3], blo1.i[3]);
  }

  Frag bones;  // bias-MFMA B: positional slots (h=0, w=0, e=0,1) = 1.0
  bones.i[0] = (h == 0) ? 0x3F803F80 : 0;
  bones.i[1] = bones.i[2] = bones.i[3] = 0;
  const int hmask = (h == 0) ? -1 : 0;  // bias A-frag lives in h==0 lanes

  __syncthreads();  // LDS tables ready

  const int4* lw = (const int4*)(smem + WTAB_OFF) + lane;  // LDS weights l<38
  const int* bc = (const int*)smem;                         // compact bias
  const int4* gw = (const int4*)(tab + WTAB_OFF) + lane;    // global l>=38

  const f32x16 zero16 = {0, 0, 0, 0, 0, 0, 0, 0, 0, 0, 0, 0, 0, 0, 0, 0};

  // Double-buffered register prefetch (parity; full unroll => static idx).
  Frag Wf[2][4];
  int nb[2];
  Wf[0][0].q = lw[0];
  Wf[0][1].q = lw[64];
  Wf[0][2].q = lw[128];
  Wf[0][3].q = lw[192];
  nb[0] = bc[n];

#pragma unroll
  for (int l = 0; l < NL; ++l) {
    const int cur = l & 1, nxt = cur ^ 1;

    // ---- ISSUE layer l+1 loads at the top of iteration l ----
    {
      const int lp = l + 1;
      const int4* src = (lp < LDS_LAYERS) ? lw : gw;  // compile-time per iter
      Wf[nxt][0].q = src[lp * 256 + 0];
      Wf[nxt][1].q = src[lp * 256 + 64];
      Wf[nxt][2].q = src[lp * 256 + 128];
      Wf[nxt][3].q = src[lp * 256 + 192];
      nb[nxt] = bc[lp * 32 + n];
    }

    // ---- SCHED BARRIER: the loads above may NOT sink below this point.
    // They drain during layer l's ~500 cyc of MFMA+split; next iteration's
    // lgkmcnt wait is then ~free. (r13/r19 failed because the scheduler
    // sank the loads back to just-before-use; this forbids that motion.)
    __builtin_amdgcn_sched_barrier(0);

    // ---- compute layer l: bias-MFMA + 6 product MFMAs (one 32x32 acc) ----
    Frag ab;
    ab.i[0] = nb[cur] & hmask;
    ab.i[1] = ab.i[2] = ab.i[3] = 0;
    f32x16 acc = MFMA32(ab.v, bones.v, zero16);
    acc = MFMA32(Wf[cur][0].v, bhi0.v, acc);  // hi x hi, kk=0
    acc = MFMA32(Wf[cur][2].v, bhi0.v, acc);  // lo x hi, kk=0
    acc = MFMA32(Wf[cur][1].v, bhi1.v, acc);  // hi x hi, kk=1
    acc = MFMA32(Wf[cur][3].v, bhi1.v, acc);  // lo x hi, kk=1
    acc = MFMA32(Wf[cur][0].v, blo0.v, acc);  // hi x lo, kk=0
    acc = MFMA32(Wf[cur][1].v, blo1.v, acc);  // hi x lo, kk=1

    // relu + trunc-split; reg-pair p -> B slot (kk=p>>2, w=p&3) [r3-verified]
#pragma unroll
    for (int p = 0; p < 8; ++p) {
      float a = fmaxf(acc[2 * p], 0.f);
      float b = fmaxf(acc[2 * p + 1], 0.f);
      int hi, lo;
      split2(a, b, hi, lo);
      if (p < 4) { bhi0.i[p] = hi; blo0.i[p] = lo; }
      else       { bhi1.i[p - 4] = hi; blo1.i[p - 4] = lo; }
    }
  }

  // ---- final layer l=40 (parity 0 buffer): same 7-MFMA body, no relu ----
  float res;
  {
    Frag ab;
    ab.i[0] = nb[0] & hmask;
    ab.i[1] = ab.i[2] = ab.i[3] = 0;
    f32x16 acc = MFMA32(ab.v, bones.v, zero16);
    acc = MFMA32(Wf[0][0].v, bhi0.v, acc);
    acc = MFMA32(Wf[0][2].v, bhi0.v, acc);
    acc = MFMA32(Wf[0][1].v, bhi1.v, acc);
    acc = MFMA32(Wf[0][3].v, bhi1.v, acc);
    acc = MFMA32(Wf[0][0].v, blo0.v, acc);
    acc = MFMA32(Wf[0][1].v, blo1.v, acc);
    res = acc[0];  // D row 0 lives in reg 0 of h==0 lanes (r3-verified)
  }

  if (h == 0) out[bbase + n] = res;
}

extern "C" void kernel_launch(void* const* d_in, const int* in_sizes, int n_in,
                              void* d_out, int out_size, void* d_ws, size_t ws_size,
                              hipStream_t stream) {
  const float* state = (const float*)d_in[0];
  const float* Wh    = (const float*)d_in[1];
  const float* bh    = (const float*)d_in[2];
  const float* Wout  = (const float*)d_in[3];
  const float* bout  = (const float*)d_in[4];
  float* out = (float*)d_out;

  build_tables<<<NL + 1, 64, 0, stream>>>(Wh, bh, Wout, bout, (char*)d_ws);

  // 4096 waves; 16 waves (1024 thr) per block; 256 blocks = 1/CU (LDS-pinned).
  policy_mfma<<<256, 1024, LDS_BYTES, stream>>>(state, (const char*)d_ws, out);
}